// Round 8
// baseline (30.974 us; speedup 1.0000x reference)
//
#include <hip/hip_runtime.h>

#define SIM_T 0.8f

typedef float f32x4 __attribute__((ext_vector_type(4)));

__device__ __forceinline__ f32x4 ntload4(const float* p) {
  return __builtin_nontemporal_load(reinterpret_cast<const f32x4*>(p));
}
__device__ __forceinline__ float ntload1(const float* p) {
  return __builtin_nontemporal_load(p);
}

// Single-dispatch path: one block per row (grid = B, 1024 threads = 16 waves).
// Each block computes its row's masked exp-sum entirely locally, takes the
// log, and contributes loss/B to res[0] via ONE device-scope atomicAdd at the
// end. No __threadfence, no cross-block reads (the R6 fence storm is avoided:
// fences, not atomics, caused the 7.5x regression).
// res must be zeroed on the stream before launch (4-byte hipMemsetAsync).
// Requires K % (4*4096) == 0.
__global__ __launch_bounds__(1024) void pruner_row(
    const float* __restrict__ out, const float* __restrict__ cs,
    float* __restrict__ res, int K, float invB) {
  const int row = blockIdx.x;
  const int tid = threadIdx.x;

  const float* crow = cs  + (size_t)row * K;
  const float* orow = out + (size_t)row * (K + 1) + 1;

  float a0 = 0.f, a1 = 0.f, a2 = 0.f, a3 = 0.f;

  // 1024 threads x 4 elems x 4 groups = 16384 elems per iteration.
  for (int kb = tid * 4; kb < K; kb += 16384) {
    // ---- issue all loads first (nontemporal: evict-first, use-once) ----
    f32x4 c0 = ntload4(crow + kb);
    f32x4 c1 = ntload4(crow + kb + 4096);
    f32x4 c2 = ntload4(crow + kb + 8192);
    f32x4 c3 = ntload4(crow + kb + 12288);
    float x00 = ntload1(orow + kb +     0), x01 = ntload1(orow + kb +     1);
    float x02 = ntload1(orow + kb +     2), x03 = ntload1(orow + kb +     3);
    float x10 = ntload1(orow + kb +  4096), x11 = ntload1(orow + kb +  4097);
    float x12 = ntload1(orow + kb +  4098), x13 = ntload1(orow + kb +  4099);
    float x20 = ntload1(orow + kb +  8192), x21 = ntload1(orow + kb +  8193);
    float x22 = ntload1(orow + kb +  8194), x23 = ntload1(orow + kb +  8195);
    float x30 = ntload1(orow + kb + 12288), x31 = ntload1(orow + kb + 12289);
    float x32 = ntload1(orow + kb + 12290), x33 = ntload1(orow + kb + 12291);
    // ---- then compute ----
    a0 += (c0.x < SIM_T) ? __expf(x00) : 0.f;
    a1 += (c0.y < SIM_T) ? __expf(x01) : 0.f;
    a2 += (c0.z < SIM_T) ? __expf(x02) : 0.f;
    a3 += (c0.w < SIM_T) ? __expf(x03) : 0.f;
    a0 += (c1.x < SIM_T) ? __expf(x10) : 0.f;
    a1 += (c1.y < SIM_T) ? __expf(x11) : 0.f;
    a2 += (c1.z < SIM_T) ? __expf(x12) : 0.f;
    a3 += (c1.w < SIM_T) ? __expf(x13) : 0.f;
    a0 += (c2.x < SIM_T) ? __expf(x20) : 0.f;
    a1 += (c2.y < SIM_T) ? __expf(x21) : 0.f;
    a2 += (c2.z < SIM_T) ? __expf(x22) : 0.f;
    a3 += (c2.w < SIM_T) ? __expf(x23) : 0.f;
    a0 += (c3.x < SIM_T) ? __expf(x30) : 0.f;
    a1 += (c3.y < SIM_T) ? __expf(x31) : 0.f;
    a2 += (c3.z < SIM_T) ? __expf(x32) : 0.f;
    a3 += (c3.w < SIM_T) ? __expf(x33) : 0.f;
  }
  float s = (a0 + a1) + (a2 + a3);

#pragma unroll
  for (int off = 32; off > 0; off >>= 1) s += __shfl_down(s, off, 64);

  __shared__ float lds[16];
  if ((tid & 63) == 0) lds[tid >> 6] = s;
  __syncthreads();

  if (tid == 0) {
    float t0 = 0.f, t1 = 0.f, t2 = 0.f, t3 = 0.f;
#pragma unroll
    for (int w = 0; w < 16; w += 4) {
      t0 += lds[w + 0];
      t1 += lds[w + 1];
      t2 += lds[w + 2];
      t3 += lds[w + 3];
    }
    const float o0 = orow[-1];
    const float t = (t0 + t1) + (t2 + t3) + __expf(o0);
    atomicAdd(res, (logf(t) - o0) * invB);
  }
}

// ---- proven two-kernel fallback (R5 structure) for unexpected shapes ----
__global__ __launch_bounds__(256) void pruner_partial_simple(
    const float* __restrict__ out, const float* __restrict__ cs,
    float* __restrict__ ws, float* __restrict__ o0s, int K, int parts) {
  const int per_part = K / parts;
  const int row  = blockIdx.x / parts;
  const int part = blockIdx.x % parts;
  const int tid  = threadIdx.x;
  const float* crow = cs  + (size_t)row * K + (size_t)part * per_part;
  const float* orow = out + (size_t)row * (K + 1) + 1 + (size_t)part * per_part;
  if (part == 0 && tid == 0) o0s[row] = orow[-1];
  float a = 0.f;
  for (int k = tid; k < per_part; k += 256)
    a += (crow[k] < SIM_T) ? __expf(orow[k]) : 0.f;
#pragma unroll
  for (int off = 32; off > 0; off >>= 1) a += __shfl_down(a, off, 64);
  __shared__ float lds[4];
  if ((tid & 63) == 0) lds[tid >> 6] = a;
  __syncthreads();
  if (tid == 0) ws[blockIdx.x] = (lds[0] + lds[1]) + (lds[2] + lds[3]);
}

__global__ __launch_bounds__(256) void pruner_final(
    const float* __restrict__ ws, const float* __restrict__ o0s,
    float* __restrict__ res, int parts, int B) {
  const int i = threadIdx.x;  // row
  float loss = 0.0f;
  if (i < B) {
    float t = 0.0f;
    for (int p = 0; p < parts; ++p) t += ws[i * parts + p];
    const float o0 = o0s[i];
    t += __expf(o0);
    loss = logf(t) - o0;
  }
#pragma unroll
  for (int off = 32; off > 0; off >>= 1) loss += __shfl_down(loss, off, 64);
  __shared__ float lds[4];
  if ((i & 63) == 0) lds[i >> 6] = loss;
  __syncthreads();
  if (i == 0) res[0] = ((lds[0] + lds[1]) + (lds[2] + lds[3])) / (float)B;
}

extern "C" void kernel_launch(void* const* d_in, const int* in_sizes, int n_in,
                              void* d_out, int out_size, void* d_ws, size_t ws_size,
                              hipStream_t stream) {
  const float* out = (const float*)d_in[0];   // [B, K+1] f32
  const float* cs  = (const float*)d_in[1];   // [B, K]   f32
  float* res = (float*)d_out;                 // scalar f32

  const int B = in_sizes[2];                  // 256
  const int K = in_sizes[1] / B;              // 65536

  if (K % 16384 == 0) {
    hipMemsetAsync(res, 0, sizeof(float), stream);
    pruner_row<<<B, 1024, 0, stream>>>(out, cs, res, K, 1.0f / (float)B);
  } else {
    const int PARTS = 8;
    float* ws  = (float*)d_ws;                // [B*PARTS] partials
    float* o0s = ws + (size_t)B * PARTS;      // [B] staged positive logits
    pruner_partial_simple<<<B * PARTS, 256, 0, stream>>>(out, cs, ws, o0s, K, PARTS);
    pruner_final<<<1, 256, 0, stream>>>(ws, o0s, res, PARTS, B);
  }
}

// Round 9
// 26.201 us; speedup vs baseline: 1.1822x; 1.1822x over previous
//
#include <hip/hip_runtime.h>

#define SIM_T 0.8f

typedef float f32x4 __attribute__((ext_vector_type(4)));

__device__ __forceinline__ f32x4 ntload4(const float* p) {
  return __builtin_nontemporal_load(reinterpret_cast<const f32x4*>(p));
}
__device__ __forceinline__ float ntload1(const float* p) {
  return __builtin_nontemporal_load(p);
}

// Kernel 1: per (row, part) masked sum of exp(output[row, 1+k]) over the
// part's slice, keeping only k where cos[row, k] < SIM_T.
// Best-known structure (R5/R7, 26.2-26.5 us): nt loads (use-once streams),
// 4x-unrolled issue-first loop, 2048 blocks (8/CU, 256 thr), o0 staging so
// the final kernel reads coalesced.
// Measured dead ends: fence-based fusion (7.5x regression — per-XCD L2
// writeback storm), 1-block-per-row single dispatch (31 us — occupancy loss),
// all-float4 repacking (+VALU, neutral mem), 4x MLP unroll (neutral).
// Effective read rate ~5.8 TB/s ~= 92% of the measured 6.29 TB/s ceiling.
__global__ __launch_bounds__(256) void pruner_partial(
    const float* __restrict__ out, const float* __restrict__ cs,
    float* __restrict__ ws, float* __restrict__ o0s, int K, int parts) {
  const int per_part = K / parts;          // 8192
  const int row  = blockIdx.x / parts;
  const int part = blockIdx.x % parts;
  const int tid  = threadIdx.x;

  const float* crow = cs  + (size_t)row * K + (size_t)part * per_part;
  const float* orow = out + (size_t)row * (K + 1) + 1 + (size_t)part * per_part;

  // stage the positive logit for the final kernel (coalesced there)
  if (part == 0 && tid == 0) o0s[row] = orow[-1];

  float a0 = 0.f, a1 = 0.f, a2 = 0.f, a3 = 0.f;

  for (int kb = tid * 4; kb < per_part; kb += 4096) {
    // ---- issue all loads first (nontemporal: evict-first, use-once) ----
    f32x4 c0 = ntload4(crow + kb);
    f32x4 c1 = ntload4(crow + kb + 1024);
    f32x4 c2 = ntload4(crow + kb + 2048);
    f32x4 c3 = ntload4(crow + kb + 3072);
    float x00 = ntload1(orow + kb +    0), x01 = ntload1(orow + kb +    1);
    float x02 = ntload1(orow + kb +    2), x03 = ntload1(orow + kb +    3);
    float x10 = ntload1(orow + kb + 1024), x11 = ntload1(orow + kb + 1025);
    float x12 = ntload1(orow + kb + 1026), x13 = ntload1(orow + kb + 1027);
    float x20 = ntload1(orow + kb + 2048), x21 = ntload1(orow + kb + 2049);
    float x22 = ntload1(orow + kb + 2050), x23 = ntload1(orow + kb + 2051);
    float x30 = ntload1(orow + kb + 3072), x31 = ntload1(orow + kb + 3073);
    float x32 = ntload1(orow + kb + 3074), x33 = ntload1(orow + kb + 3075);
    // ---- then compute ----
    a0 += (c0.x < SIM_T) ? __expf(x00) : 0.f;
    a1 += (c0.y < SIM_T) ? __expf(x01) : 0.f;
    a2 += (c0.z < SIM_T) ? __expf(x02) : 0.f;
    a3 += (c0.w < SIM_T) ? __expf(x03) : 0.f;
    a0 += (c1.x < SIM_T) ? __expf(x10) : 0.f;
    a1 += (c1.y < SIM_T) ? __expf(x11) : 0.f;
    a2 += (c1.z < SIM_T) ? __expf(x12) : 0.f;
    a3 += (c1.w < SIM_T) ? __expf(x13) : 0.f;
    a0 += (c2.x < SIM_T) ? __expf(x20) : 0.f;
    a1 += (c2.y < SIM_T) ? __expf(x21) : 0.f;
    a2 += (c2.z < SIM_T) ? __expf(x22) : 0.f;
    a3 += (c2.w < SIM_T) ? __expf(x23) : 0.f;
    a0 += (c3.x < SIM_T) ? __expf(x30) : 0.f;
    a1 += (c3.y < SIM_T) ? __expf(x31) : 0.f;
    a2 += (c3.z < SIM_T) ? __expf(x32) : 0.f;
    a3 += (c3.w < SIM_T) ? __expf(x33) : 0.f;
  }
  float s = (a0 + a1) + (a2 + a3);

#pragma unroll
  for (int off = 32; off > 0; off >>= 1) s += __shfl_down(s, off, 64);

  __shared__ float lds[4];
  if ((tid & 63) == 0) lds[tid >> 6] = s;
  __syncthreads();
  if (tid == 0) ws[blockIdx.x] = (lds[0] + lds[1]) + (lds[2] + lds[3]);
}

// Generic fallback for shapes where per_part % 4096 != 0.
__global__ __launch_bounds__(256) void pruner_partial_simple(
    const float* __restrict__ out, const float* __restrict__ cs,
    float* __restrict__ ws, float* __restrict__ o0s, int K, int parts) {
  const int per_part = K / parts;
  const int row  = blockIdx.x / parts;
  const int part = blockIdx.x % parts;
  const int tid  = threadIdx.x;
  const float* crow = cs  + (size_t)row * K + (size_t)part * per_part;
  const float* orow = out + (size_t)row * (K + 1) + 1 + (size_t)part * per_part;
  if (part == 0 && tid == 0) o0s[row] = orow[-1];
  float a = 0.f;
  for (int k = tid; k < per_part; k += 256)
    a += (crow[k] < SIM_T) ? __expf(orow[k]) : 0.f;
#pragma unroll
  for (int off = 32; off > 0; off >>= 1) a += __shfl_down(a, off, 64);
  __shared__ float lds[4];
  if ((tid & 63) == 0) lds[tid >> 6] = a;
  __syncthreads();
  if (tid == 0) ws[blockIdx.x] = (lds[0] + lds[1]) + (lds[2] + lds[3]);
}

// Kernel 2: one block of B threads; everything it reads is coalesced
// (partials + staged o0). Thread i -> row i; block-reduce the mean.
__global__ __launch_bounds__(256) void pruner_final(
    const float* __restrict__ ws, const float* __restrict__ o0s,
    float* __restrict__ res, int parts, int B) {
  const int i = threadIdx.x;  // row
  float loss = 0.0f;
  if (i < B) {
    float t = 0.0f;
    for (int p = 0; p < parts; ++p) t += ws[i * parts + p];
    const float o0 = o0s[i];
    t += __expf(o0);
    loss = logf(t) - o0;
  }
#pragma unroll
  for (int off = 32; off > 0; off >>= 1) loss += __shfl_down(loss, off, 64);
  __shared__ float lds[4];
  if ((i & 63) == 0) lds[i >> 6] = loss;
  __syncthreads();
  if (i == 0) res[0] = ((lds[0] + lds[1]) + (lds[2] + lds[3])) / (float)B;
}

extern "C" void kernel_launch(void* const* d_in, const int* in_sizes, int n_in,
                              void* d_out, int out_size, void* d_ws, size_t ws_size,
                              hipStream_t stream) {
  const float* out = (const float*)d_in[0];   // [B, K+1] f32
  const float* cs  = (const float*)d_in[1];   // [B, K]   f32
  float* res = (float*)d_out;                 // scalar f32

  const int B = in_sizes[2];                  // 256
  const int K = in_sizes[1] / B;              // 65536

  const int PARTS = 8;                        // 2048 blocks = 8/CU
  float* ws  = (float*)d_ws;                  // [B*PARTS] partials
  float* o0s = ws + (size_t)B * PARTS;        // [B] staged positive logits

  if ((K / PARTS) % 4096 == 0) {
    pruner_partial<<<B * PARTS, 256, 0, stream>>>(out, cs, ws, o0s, K, PARTS);
  } else {
    pruner_partial_simple<<<B * PARTS, 256, 0, stream>>>(out, cs, ws, o0s, K, PARTS);
  }
  pruner_final<<<1, 256, 0, stream>>>(ws, o0s, res, PARTS, B);
}